// Round 24
// baseline (15.121 us; speedup 1.0000x reference)
//
#include <hip/hip_runtime.h>
#include <hip/hip_fp16.h>
#include <math.h>

// GaussianMixtureLoss: loss = CONST - mean_{b,n}( ln sum_m exp(p·g - |g|²/2) - |p|²/2 )
// B=4, N=4096, M=4096, D=3, SIGMA=1.
// R24: R23 (MFMA Schraudolph, 15.03us) + three K1 fixes:
//  1. staging via float2 pairs (12 coalesced loads vs 24 scalar),
//  2. 2-way software-pipelined inner (2 ds_reads -> 2 MFMAs -> 2 consume
//     chains into separate accumulators; hides MFMA latency),
//  3. hi-lane B-frag zeroing via stride-0 zero-slot (no per-tile cndmask).
// MFMA algebra unchanged: quad (sqrtK*p,32768)x(sqrtK*g,a4) ->
// Schraudolph-domain dot; VALU = cvt+add per exp. C/D layout m74/m101.
#define BATCH 4
#define NPTS 4096
#define NMIX 4096
#define THREADS 512
#define PPB 32                 // points per block (one 32-row MFMA tile)
#define NBLOCKS ((BATCH * NPTS) / PPB)  // 512
#define NTILES (NMIX / 32)     // 128 mixture tiles per batch
#define TPW (NTILES / 8)       // 16 tiles per wave (8 waves)

#define LN2 0.6931471805599453f
#define CONST_TERM 0.9189385332046727f  // 0.5*log(2*pi)
#define INV_COUNT (1.0f / (float)(BATCH * NPTS))
// Schraudolph: K = 2^23*log2(e); BIAS = 2^23*(127-0.0563)
#define SQK      3478.8221f          // sqrt(K)
#define B4VAL    32768.0f            // exact in f16
#define A4BASE   32497.587f          // BIAS / 32768
#define A4SLOPE  (-184.66497f)       // -(K/2) / 32768

typedef _Float16 f16x4 __attribute__((ext_vector_type(4)));
typedef float f32x16 __attribute__((ext_vector_type(16)));

__device__ __forceinline__ float fast_log2(float x) {
#if __has_builtin(__builtin_amdgcn_logf)
  return __builtin_amdgcn_logf(x);
#else
  return log2f(x);
#endif
}

__device__ __forceinline__ uint32_t pack_h2(float a, float b) {
  __half2 h = __float22half2_rn(make_float2(a, b));
  return __builtin_bit_cast(uint32_t, h);
}

__global__ __launch_bounds__(THREADS) void gm_main(
    const float* __restrict__ pred, const float* __restrict__ gt,
    float* __restrict__ bsum) {
  __shared__ __align__(8) uint2 gsh[NMIX + 1];  // 32KB quads + zero slot
  __shared__ float comb[8][PPB];                // per-wave partial rows
  __shared__ float wred[16];

  const int t = threadIdx.x;
  const int b = blockIdx.x >> 7;            // 128 blocks per batch
  const int n0 = (blockIdx.x & 127) * PPB;
  const int lane = t & 63;
  const int w = t >> 6;                     // wave 0..7

  // ---- stage mixture quads (sqrtK*g, a4), float2-pair pattern ----
#pragma unroll
  for (int i = 0; i < NMIX / (2 * THREADS); ++i) {  // 4 pairs per thread
    int s = t + i * THREADS;  // pair index 0..2047
    const float2* g = (const float2*)(gt + ((size_t)(b * NMIX + 2 * s)) * 3);
    float2 g01 = g[0], g23 = g[1], g45 = g[2];
    // mixture 2s: (g01.x, g01.y, g23.x); 2s+1: (g23.y, g45.x, g45.y)
    float n20 = fmaf(g01.x, g01.x, fmaf(g01.y, g01.y, g23.x * g23.x));
    float n21 = fmaf(g23.y, g23.y, fmaf(g45.x, g45.x, g45.y * g45.y));
    float a40 = fmaf(n20, A4SLOPE, A4BASE);
    float a41 = fmaf(n21, A4SLOPE, A4BASE);
    gsh[2 * s] = make_uint2(pack_h2(SQK * g01.x, SQK * g01.y),
                            pack_h2(SQK * g23.x, a40));
    gsh[2 * s + 1] = make_uint2(pack_h2(SQK * g23.y, SQK * g45.x),
                                pack_h2(SQK * g45.y, a41));
  }
  if (t == 0) gsh[NMIX] = make_uint2(0u, 0u);  // zero slot for hi lanes

  // ---- A-frag (points), loop-invariant: lane<32 -> point n0+lane ----
  f16x4 afrag;
  {
    uint2 au = make_uint2(0u, 0u);
    if (lane < 32) {
      const float* p = pred + (size_t)(b * NPTS + n0 + lane) * 3;
      au = make_uint2(pack_h2(SQK * p[0], SQK * p[1]),
                      pack_h2(SQK * p[2], B4VAL));
    }
    afrag = __builtin_bit_cast(f16x4, au);
  }

  __syncthreads();

  // ---- inner: 16 tiles/wave, 2-way pipelined MFMA + cvt/add ----
  f32x16 acc = 0.0f, acc2 = 0.0f;
  {
    const bool lo = lane < 32;
    // lo lanes walk the wave's tile strip; hi lanes camp on the zero slot
    int idx = lo ? (w * (TPW * 32) + lane) : NMIX;
    const int step = lo ? 32 : 0;
    const f32x16 czero = 0.0f;
#pragma unroll 2
    for (int j = 0; j < TPW; j += 2) {
      uint2 ra = gsh[idx];
      uint2 rb = gsh[idx + step];
      idx += 2 * step;
      f16x4 bfa = __builtin_bit_cast(f16x4, ra);
      f16x4 bfb = __builtin_bit_cast(f16x4, rb);
      f32x16 d0 = __builtin_amdgcn_mfma_f32_32x32x8f16(afrag, bfa, czero, 0, 0, 0);
      f32x16 d1 = __builtin_amdgcn_mfma_f32_32x32x8f16(afrag, bfb, czero, 0, 0, 0);
#pragma unroll
      for (int r = 0; r < 16; ++r)
        acc[r] += __builtin_bit_cast(float, (int)d0[r]);   // Schraudolph exp
#pragma unroll
      for (int r = 0; r < 16; ++r)
        acc2[r] += __builtin_bit_cast(float, (int)d1[r]);
    }
  }
#pragma unroll
  for (int r = 0; r < 16; ++r) acc[r] += acc2[r];

  // ---- col-reduce: sum 32 mixture-cols (xor over lane bits 0-4) ----
#pragma unroll
  for (int mask = 1; mask <= 16; mask <<= 1) {
#pragma unroll
    for (int r = 0; r < 16; ++r) acc[r] += __shfl_xor(acc[r], mask, 64);
  }

  // rows: (r&3) + 8*(r>>2) + 4*(lane>>5); lanes 0 and 32 write 16 rows each
  if ((lane & 31) == 0) {
#pragma unroll
    for (int r = 0; r < 16; ++r)
      comb[w][(r & 3) + 8 * (r >> 2) + 4 * (lane >> 5)] = acc[r];
  }
  __syncthreads();

  // ---- tail: combine 8 waves, log, hp2, block reduce ----
  if (t < PPB) {
    float s = ((comb[0][t] + comb[1][t]) + (comb[2][t] + comb[3][t])) +
              ((comb[4][t] + comb[5][t]) + (comb[6][t] + comb[7][t]));
    const float* p = pred + (size_t)(b * NPTS + n0 + t) * 3;
    float hp2 = 0.5f * (p[0] * p[0] + p[1] * p[1] + p[2] * p[2]);
    float ll = (LN2 * fast_log2(s) - hp2) * INV_COUNT;
#pragma unroll
    for (int off = 16; off > 0; off >>= 1) ll += __shfl_down(ll, off, 32);
    if (t == 0) bsum[blockIdx.x] = ll;
  }
}

__global__ __launch_bounds__(256) void gm_reduce(
    const float* __restrict__ bsum, float* __restrict__ out) {
  const int t = threadIdx.x;
  float v = bsum[t] + bsum[t + 256];  // 512 entries
  for (int off = 32; off > 0; off >>= 1) v += __shfl_down(v, off, 64);
  __shared__ float w[4];
  if ((t & 63) == 0) w[t >> 6] = v;
  __syncthreads();
  if (t == 0) out[0] = CONST_TERM - ((w[0] + w[1]) + (w[2] + w[3]));
}

extern "C" void kernel_launch(void* const* d_in, const int* in_sizes, int n_in,
                              void* d_out, int out_size, void* d_ws, size_t ws_size,
                              hipStream_t stream) {
  const float* pred = (const float*)d_in[0];
  const float* gt   = (const float*)d_in[1];
  float* out = (float*)d_out;
  float* bsum = (float*)d_ws;  // 512 floats, fully overwritten every call

  gm_main<<<NBLOCKS, THREADS, 0, stream>>>(pred, gt, bsum);
  gm_reduce<<<1, 256, 0, stream>>>(bsum, out);
}